// Round 4
// baseline (600.386 us; speedup 1.0000x reference)
//
#include <hip/hip_runtime.h>

// RegimeAwareStudent: B=524288 tokens, ALL tensors fp32, rid int32, out fp32.
//   h  = relu(x @ fe_w1 + fe_b1)           [B,128]->[B,256]
//   f  = relu(h @ fe_w2 + fe_b2)           [B,256]->[B,128]
//   c  = concat(f, emb[rid])               [B,192]
//   eh = relu(c @ ew1[rid] + eb1[rid])     [B,192]->[B,256]
//   o  = eh @ ew2[rid] + eb2[rid]          [B,256]->[B,1]
// R4: global counting sort by regime (64-aligned segments) -> every 64-token
// tile is single-regime; stage 3 restructured kt-outer/m-inner so each ew1
// B-fragment is loaded once per block and reused x4 (was: reloaded per m-tile,
// ~5.8 GB of L2 traffic -> now ~1.8 GB). Compute in bf16 MFMA, fp32 accum.

typedef short short8 __attribute__((ext_vector_type(8)));
typedef float f32x4  __attribute__((ext_vector_type(4)));

#define MFMA16 __builtin_amdgcn_mfma_f32_16x16x32_bf16

constexpr int B_TOK  = 524288;
constexpr int TM     = 64;                 // tokens per tile
constexpr int NTILES = B_TOK / TM + 3;     // 8195 (segments 64-padded)

// workspace layout
constexpr size_t PW1_OFF   = 0;            // fe_w1 pack: 32768 ushort
constexpr size_t PW2_OFF   = 32768;        // fe_w2 pack: 32768 ushort
constexpr size_t PE1_OFF   = 65536;        // ew1 pack: 3*49152 ushort
constexpr size_t PE1_PER_R = 49152;
constexpr size_t CTRL_BYTE_OFF = 425984;   // 16 ints: [0..2]=counts [4..7]=bases [8..10]=cursors
constexpr size_t PERM_BYTE_OFF = 426048;
constexpr int PERM_LEN = NTILES * TM;      // 524480  (total ws ~2.52 MB)

static __device__ __forceinline__ ushort f2bf(float f) {  // RNE
    union { float f; unsigned int i; } x; x.f = f;
    unsigned int i = x.i;
    i += 0x7fffu + ((i >> 16) & 1u);
    return (ushort)(i >> 16);
}

// ---- weight repack: fp32 -> bf16 MFMA B-fragment layout -------------------
// pw[frag=kt*NT+nt][lane][j] = bf16(W[kt*32 + (lane>>4)*8 + j][nt*16 + (lane&15)])
__global__ void repack_weights(const float* __restrict__ w1,
                               const float* __restrict__ w2,
                               const float* __restrict__ e1,
                               ushort* __restrict__ pw) {
    int t = blockIdx.x * 256 + threadIdx.x;       // 26624 threads total
    const float* src; int N, kt, nt; size_t dst;
    int lane = t & 63;
    if (t < 4096) {                                // fe_w1: K=128,N=256
        int frag = t >> 6; kt = frag >> 4; nt = frag & 15;
        src = w1; N = 256; dst = PW1_OFF + (size_t)t * 8;
    } else if (t < 8192) {                         // fe_w2: K=256,N=128
        int u = t - 4096; int frag = u >> 6; kt = frag >> 3; nt = frag & 7;
        src = w2; N = 128; dst = PW2_OFF + (size_t)u * 8;
    } else {                                       // ew1[r]: K=192,N=256
        int u = t - 8192; int reg = u / 6144; int v = u % 6144;
        int frag = v >> 6; kt = frag >> 4; nt = frag & 15;
        src = e1 + (size_t)reg * (192 * 256); N = 256;
        dst = PE1_OFF + (size_t)reg * PE1_PER_R + (size_t)v * 8;
    }
    int quad = lane >> 4, cc = lane & 15;
    int k0 = kt * 32 + quad * 8;
    int n  = nt * 16 + cc;
    short8 vv;
    #pragma unroll
    for (int j = 0; j < 8; ++j) vv[j] = (short)f2bf(src[(size_t)(k0 + j) * N + n]);
    *(short8*)(pw + dst) = vv;
}

// ---- regime histogram ------------------------------------------------------
__global__ void count_regimes(const int* __restrict__ rid, int* __restrict__ ctrl) {
    int lane = threadIdx.x & 63;
    int base = blockIdx.x * 2048 + threadIdx.x;
    int myr[8];
    #pragma unroll
    for (int i = 0; i < 8; ++i) myr[i] = rid[base + i * 256];
    #pragma unroll
    for (int r = 0; r < 3; ++r) {
        int tot = 0;
        #pragma unroll
        for (int i = 0; i < 8; ++i) tot += __popcll(__ballot(myr[i] == r));
        if (lane == 0) atomicAdd(&ctrl[r], tot);
    }
}

__global__ void compute_bases(int* __restrict__ ctrl) {
    int c0 = ctrl[0], c1 = ctrl[1];
    int a0 = (c0 + 63) & ~63, a1 = (c1 + 63) & ~63;
    int c2 = ctrl[2]; int a2 = (c2 + 63) & ~63;
    ctrl[4] = 0; ctrl[5] = a0; ctrl[6] = a0 + a1; ctrl[7] = a0 + a1 + a2;
}

// ---- build permutation (3 atomics per wave) -------------------------------
__global__ void scatter_perm(const int* __restrict__ rid, int* __restrict__ ctrl,
                             int* __restrict__ perm) {
    int lane = threadIdx.x & 63;
    int base_idx = blockIdx.x * 2048 + threadIdx.x;
    unsigned long long below = (1ull << lane) - 1ull;
    int myr[8];
    #pragma unroll
    for (int i = 0; i < 8; ++i) myr[i] = rid[base_idx + i * 256];
    #pragma unroll
    for (int r = 0; r < 3; ++r) {
        unsigned long long masks[8];
        int pre[8], tot = 0;
        #pragma unroll
        for (int i = 0; i < 8; ++i) {
            masks[i] = __ballot(myr[i] == r);
            pre[i] = tot;
            tot += __popcll(masks[i]);
        }
        int old = 0;
        if (lane == 0) old = atomicAdd(&ctrl[8 + r], tot);
        old = __shfl(old, 0);
        int seg = ctrl[4 + r];
        #pragma unroll
        for (int i = 0; i < 8; ++i)
            if (myr[i] == r)
                perm[seg + old + pre[i] + __popcll(masks[i] & below)] =
                    base_idx + i * 256;
    }
}

// ---- fused main: 64-token single-regime tile, full MLP chain --------------
// 256 threads = 4 waves; wave w owns an output-column quarter of each GEMM.
// All three GEMM stages are kt-outer/m-inner: each B-fragment global load is
// reused x4 across m-tiles (weight traffic = one pack read per block).
__global__ __launch_bounds__(256, 2) void fused_main(
    const float* __restrict__ x,
    const int*   __restrict__ ctrl,
    const int*   __restrict__ perm,
    const ushort* __restrict__ pw,
    const float* __restrict__ fe_b1,
    const float* __restrict__ fe_b2,
    const float* __restrict__ emb,
    const float* __restrict__ eb1,
    const float* __restrict__ ew2,
    const float* __restrict__ eb2,
    float*       __restrict__ out) {
    __shared__ ushort sA[64 * 200];  // X tile (stride 136), then C tile (stride 200)
    __shared__ ushort sH[64 * 264];  // H tile (stride 264); later float red[64][4]

    const int t    = threadIdx.x;
    const int w    = t >> 6;
    const int lane = t & 63;
    const int quad = lane >> 4;
    const int c    = lane & 15;
    const int ts   = blockIdx.x * TM;
    const int r    = (ts >= ctrl[5]) + (ts >= ctrl[6]);  // tile regime (segment-aligned)

    // ---- gather X rows (fp32 -> bf16) via global perm; padding rows -> 0 ----
    #pragma unroll
    for (int it = 0; it < 4; ++it) {
        int chunk = it * 256 + t;
        int row = chunk >> 4, seg = chunk & 15;   // 8 floats per chunk
        int g = perm[ts + row];
        f32x4 f0 = {0.f, 0.f, 0.f, 0.f}, f1 = {0.f, 0.f, 0.f, 0.f};
        if (g >= 0) {
            const float* xr = x + (size_t)g * 128 + seg * 8;
            f0 = *(const f32x4*)xr;
            f1 = *(const f32x4*)(xr + 4);
        }
        short8 v;
        #pragma unroll
        for (int j = 0; j < 4; ++j) { v[j] = (short)f2bf(f0[j]); v[4 + j] = (short)f2bf(f1[j]); }
        *(short8*)(&sA[row * 136 + seg * 8]) = v;
    }
    __syncthreads();

    // ---- stage 1: H = relu(X @ W1 + b1); wave cols [w*64, w*64+64) ----
    {
        f32x4 acc[4][4] = {};
        #pragma unroll
        for (int kt = 0; kt < 4; ++kt) {
            short8 a[4], b[4];
            #pragma unroll
            for (int m = 0; m < 4; ++m)
                a[m] = *(const short8*)(&sA[(m * 16 + c) * 136 + kt * 32 + quad * 8]);
            #pragma unroll
            for (int nn = 0; nn < 4; ++nn)
                b[nn] = *(const short8*)(pw + PW1_OFF +
                        ((size_t)((kt * 16 + (w * 4 + nn)) * 64 + lane)) * 8);
            #pragma unroll
            for (int m = 0; m < 4; ++m)
                #pragma unroll
                for (int nn = 0; nn < 4; ++nn)
                    acc[m][nn] = MFMA16(a[m], b[nn], acc[m][nn], 0, 0, 0);
        }
        float b1v[4];
        #pragma unroll
        for (int nn = 0; nn < 4; ++nn) b1v[nn] = fe_b1[w * 64 + nn * 16 + c];
        #pragma unroll
        for (int m = 0; m < 4; ++m)
            #pragma unroll
            for (int nn = 0; nn < 4; ++nn)
                #pragma unroll
                for (int i = 0; i < 4; ++i) {
                    float v = fmaxf(acc[m][nn][i] + b1v[nn], 0.0f);
                    sH[(m * 16 + quad * 4 + i) * 264 + w * 64 + nn * 16 + c] = f2bf(v);
                }
    }
    __syncthreads();

    // ---- stage 2: F = relu(H @ W2 + b2); wave cols [w*32, w*32+32) ----
    {
        f32x4 acc[4][2] = {};
        #pragma unroll
        for (int kt = 0; kt < 8; ++kt) {
            short8 a[4], b[2];
            #pragma unroll
            for (int m = 0; m < 4; ++m)
                a[m] = *(const short8*)(&sH[(m * 16 + c) * 264 + kt * 32 + quad * 8]);
            #pragma unroll
            for (int nn = 0; nn < 2; ++nn)
                b[nn] = *(const short8*)(pw + PW2_OFF +
                        ((size_t)((kt * 8 + (w * 2 + nn)) * 64 + lane)) * 8);
            #pragma unroll
            for (int m = 0; m < 4; ++m)
                #pragma unroll
                for (int nn = 0; nn < 2; ++nn)
                    acc[m][nn] = MFMA16(a[m], b[nn], acc[m][nn], 0, 0, 0);
        }
        float b2v[2];
        #pragma unroll
        for (int nn = 0; nn < 2; ++nn) b2v[nn] = fe_b2[w * 32 + nn * 16 + c];
        #pragma unroll
        for (int m = 0; m < 4; ++m)
            #pragma unroll
            for (int nn = 0; nn < 2; ++nn)
                #pragma unroll
                for (int i = 0; i < 4; ++i) {
                    float v = fmaxf(acc[m][nn][i] + b2v[nn], 0.0f);
                    sA[(m * 16 + quad * 4 + i) * 200 + w * 32 + nn * 16 + c] = f2bf(v);
                }
    }
    // append regime embedding (broadcast; single regime per tile) to cols [128,192)
    #pragma unroll
    for (int it = 0; it < 2; ++it) {
        int chunk = it * 256 + t;
        int row = chunk >> 3, seg = chunk & 7;    // 8 floats per chunk
        const float* ep = emb + r * 64 + seg * 8;
        f32x4 f0 = *(const f32x4*)ep;
        f32x4 f1 = *(const f32x4*)(ep + 4);
        short8 e;
        #pragma unroll
        for (int j = 0; j < 4; ++j) { e[j] = (short)f2bf(f0[j]); e[4 + j] = (short)f2bf(f1[j]); }
        *(short8*)(&sA[row * 200 + 128 + seg * 8]) = e;
    }
    __syncthreads();

    // ---- stage 3: EH = relu(C @ EW1[r] + eb1[r]); fused dot with ew2[r] ----
    // kt-outer / m-inner: each B-fragment loaded once, reused x4.
    {
        f32x4 acc[4][4] = {};
        const ushort* pe = pw + PE1_OFF + (size_t)r * PE1_PER_R;
        #pragma unroll
        for (int kt = 0; kt < 6; ++kt) {
            short8 a[4], b[4];
            #pragma unroll
            for (int m = 0; m < 4; ++m)
                a[m] = *(const short8*)(&sA[(m * 16 + c) * 200 + kt * 32 + quad * 8]);
            #pragma unroll
            for (int nn = 0; nn < 4; ++nn)
                b[nn] = *(const short8*)(pe +
                        ((size_t)((kt * 16 + (w * 4 + nn)) * 64 + lane)) * 8);
            #pragma unroll
            for (int m = 0; m < 4; ++m)
                #pragma unroll
                for (int nn = 0; nn < 4; ++nn)
                    acc[m][nn] = MFMA16(a[m], b[nn], acc[m][nn], 0, 0, 0);
        }
        float eb1v[4], w2v[4];
        #pragma unroll
        for (int nn = 0; nn < 4; ++nn) {
            int col = w * 64 + nn * 16 + c;
            eb1v[nn] = eb1[r * 256 + col];
            w2v[nn]  = ew2[r * 256 + col];
        }
        float* red = (float*)sH;  // sH dead after stage-2 barrier
        #pragma unroll
        for (int m = 0; m < 4; ++m) {
            float s[4] = {0.f, 0.f, 0.f, 0.f};
            #pragma unroll
            for (int nn = 0; nn < 4; ++nn)
                #pragma unroll
                for (int i = 0; i < 4; ++i)
                    s[i] += fmaxf(acc[m][nn][i] + eb1v[nn], 0.0f) * w2v[nn];
            #pragma unroll
            for (int i = 0; i < 4; ++i) {     // reduce over 16 cols (lane bits 0..3)
                s[i] += __shfl_xor(s[i], 1);
                s[i] += __shfl_xor(s[i], 2);
                s[i] += __shfl_xor(s[i], 4);
                s[i] += __shfl_xor(s[i], 8);
            }
            if (c == 0)
                #pragma unroll
                for (int i = 0; i < 4; ++i)
                    red[(m * 16 + quad * 4 + i) * 4 + w] = s[i];
        }
    }
    __syncthreads();

    // ---- final: sum 4 wave-partials + eb2[regime], scatter fp32 out ----
    if (t < 64) {
        const float* red = (const float*)sH;
        float sum = red[t * 4 + 0] + red[t * 4 + 1] + red[t * 4 + 2] + red[t * 4 + 3]
                    + eb2[r];
        int g = perm[ts + t];
        if (g >= 0) out[g] = sum;
    }
}

extern "C" void kernel_launch(void* const* d_in, const int* in_sizes, int n_in,
                              void* d_out, int out_size, void* d_ws, size_t ws_size,
                              hipStream_t stream) {
    const float* x     = (const float*)d_in[0];
    const int*   rid   = (const int*)d_in[1];
    const float* fe_w1 = (const float*)d_in[2];
    const float* fe_b1 = (const float*)d_in[3];
    const float* fe_w2 = (const float*)d_in[4];
    const float* fe_b2 = (const float*)d_in[5];
    const float* emb   = (const float*)d_in[6];
    const float* ew1   = (const float*)d_in[7];
    const float* eb1   = (const float*)d_in[8];
    const float* ew2   = (const float*)d_in[9];
    const float* eb2   = (const float*)d_in[10];
    float* out = (float*)d_out;

    ushort* pw   = (ushort*)d_ws;
    int*    ctrl = (int*)((char*)d_ws + CTRL_BYTE_OFF);
    int*    perm = (int*)((char*)d_ws + PERM_BYTE_OFF);

    hipMemsetAsync(ctrl, 0, 64, stream);
    hipMemsetAsync(perm, 0xFF, (size_t)PERM_LEN * 4, stream);  // perm = -1 (padding)

    hipLaunchKernelGGL(repack_weights, dim3(104), dim3(256), 0, stream,
                       fe_w1, fe_w2, ew1, pw);
    hipLaunchKernelGGL(count_regimes, dim3(256), dim3(256), 0, stream, rid, ctrl);
    hipLaunchKernelGGL(compute_bases, dim3(1), dim3(1), 0, stream, ctrl);
    hipLaunchKernelGGL(scatter_perm, dim3(256), dim3(256), 0, stream, rid, ctrl, perm);
    hipLaunchKernelGGL(fused_main, dim3(NTILES), dim3(256), 0, stream,
                       x, ctrl, perm, pw, fe_b1, fe_b2, emb, eb1, ew2, eb2, out);
}